// Round 3
// baseline (499.304 us; speedup 1.0000x reference)
//
#include <hip/hip_runtime.h>

#define Tdim 200
#define Ddim 128
#define Hdim 64
#define NBS  3200
#define NEGV (-1e10f)

typedef _Float16 f16x8 __attribute__((ext_vector_type(8)));
typedef float    floatx4 __attribute__((ext_vector_type(4)));

__device__ __forceinline__ unsigned int packf16(float a, float b) {
    _Float16 ha = (_Float16)a, hb = (_Float16)b;
    unsigned int ua = *(unsigned short*)&ha, ub = *(unsigned short*)&hb;
    return ua | (ub << 16);
}

__device__ __forceinline__ float ftanh(float x) {
    // tanh(x) = 1 - 2/(exp(2x)+1); overflow -> rcp(inf)=0 -> 1 (correct tail)
    float e = __expf(2.0f * x);
    return 1.0f - 2.0f * __builtin_amdgcn_rcpf(e + 1.0f);
}

// one block (4 waves) per (b,s). ONE barrier total:
//  - wave wv stages rows [48wv,48wv+48) (wave3: 56) and runs GEMM1 on exactly those
//    rows -> stage->GEMM1 dependency is wave-local (lgkmcnt-ordered, no barrier).
//  - w2h computed redundantly per wave in registers (shfl over quad) -> no barrier.
//  - mask applied at attL-write time in GEMM1 -> attL holds masked logits.
//  - barrier: attL + all xs rows visible.
//  - softmax is wave-local: each thread reads the 13 logits its pass-2 t-set needs,
//    max/sum butterfly over tg-lanes (xor 4,8,16,32; each t counted once), att stays
//    in the registers pass 2 consumes. No further barriers; direct global store.
//
// LDS X: fp16, 16B units; element (t,k) at unit t*16 + ((k>>3) ^ (t&15)), byte (k&7)*2.
// XOR swizzle: conflict-free ds_read_b128 for MFMA A-frags AND pass-2 row reads.
__global__ __launch_bounds__(256, 3) void attn_main(
    const float* __restrict__ X, const float* __restrict__ z,
    const int* __restrict__ mask,
    const float* __restrict__ W1, const float* __restrict__ W2w,
    const float* __restrict__ W2b,
    const float* __restrict__ Vw, const float* __restrict__ Vb,
    float* __restrict__ out)
{
    __shared__ __align__(16) unsigned short xs[Tdim * 128];  // 51200 B, swizzled fp16
    __shared__ float attL[Tdim];                             // masked logits
    // total LDS = 52000 B -> 3 blocks/CU (12 waves)

    const int tid = threadIdx.x;
    const int bs  = blockIdx.x;
    const float* __restrict__ Xb = X + (size_t)bs * (Tdim * Ddim);
    const int* __restrict__ maskb = mask + bs * Tdim;
    const int lane = tid & 63;
    const int wv   = tid >> 6;
    const int l15  = lane & 15, quad = lane >> 4;

    // ---- warm mask row into L2 (used via int4 in GEMM1); keep-alive vs DCE
    if (tid < Tdim) {
        int mv_ = maskb[tid];
        asm volatile("" :: "v"(mv_));
    }

    // ---- wave-local staging of this wave's rows (coalesced 1KB per wave-load)
    const int R0  = wv * 48;
    const int nIt = (wv == 3) ? 28 : 24; // rows*32/64
    #pragma unroll 4
    for (int i = 0; i < nIt; ++i) {
        int j = i * 64 + lane;
        int t = R0 + (j >> 5), dq = j & 31;
        float4 v = *(const float4*)(Xb + t * Ddim + dq * 4);
        unsigned int lo = packf16(v.x, v.y);
        unsigned int hi = packf16(v.z, v.w);
        int u16 = t * 16 + ((dq >> 1) ^ (t & 15));
        *(uint2*)((char*)xs + u16 * 16 + (dq & 1) * 8) = make_uint2(lo, hi);
    }

    // ---- w2h redundant per wave, in registers (no LDS, no barrier):
    // lane: partial dots for h = l15+16n over d in [quad*32, quad*32+32); reduce quad.
    float w2[4];
    {
        const float4* zp = (const float4*)(z + (size_t)bs * 128 + quad * 32);
        float4 zv[8];
        #pragma unroll
        for (int i = 0; i < 8; ++i) zv[i] = zp[i];
        #pragma unroll
        for (int n = 0; n < 4; ++n) {
            const float4* wp = (const float4*)(W2w + (l15 + 16 * n) * 128 + quad * 32);
            float a = 0.f;
            #pragma unroll
            for (int i = 0; i < 8; ++i) {
                float4 wv4 = wp[i];
                a = fmaf(zv[i].x, wv4.x, a); a = fmaf(zv[i].y, wv4.y, a);
                a = fmaf(zv[i].z, wv4.z, a); a = fmaf(zv[i].w, wv4.w, a);
            }
            w2[n] = a;
        }
        #pragma unroll
        for (int n = 0; n < 4; ++n) {
            w2[n] += __shfl_xor(w2[n], 16);
            w2[n] += __shfl_xor(w2[n], 32);
            w2[n] += W2b[l15 + 16 * n];
        }
    }

    // ---- B fragments from global W1 fp32 (32KB, L2-hot): B[n][k] = W1[h=n][d=k]
    f16x8 bfrag[4][4];
    #pragma unroll
    for (int n = 0; n < 4; ++n)
        #pragma unroll
        for (int ks = 0; ks < 4; ++ks) {
            const float* wp = W1 + (n * 16 + l15) * 128 + ks * 32 + quad * 8;
            float4 v0 = *(const float4*)wp;
            float4 v1 = *(const float4*)(wp + 4);
            uint4 u = make_uint4(packf16(v0.x, v0.y), packf16(v0.z, v0.w),
                                 packf16(v1.x, v1.y), packf16(v1.z, v1.w));
            bfrag[n][ks] = *(f16x8*)&u;
        }

    const float Vb0 = Vb[0];
    float vwr[4];
    #pragma unroll
    for (int n = 0; n < 4; ++n) vwr[n] = Vw[l15 + 16 * n];

    // ---- GEMM1 + logits on OWN rows: wave wv -> tiles [3wv, 3wv+3) (wave3: 9..12)
    // tile 12 = rows 184..199 overlaps tile 11; same wave recomputes identical
    // values serially -> benign same-bits double write, no race.
    const int mtEnd = (wv == 3) ? 13 : wv * 3 + 3;
    for (int mt = wv * 3; mt < mtEnd; ++mt) {
        const int t0 = (mt == 12) ? 184 : mt * 16;
        const int trow = t0 + l15;
        floatx4 acc[4];
        #pragma unroll
        for (int n = 0; n < 4; ++n) acc[n] = (floatx4){0.f, 0.f, 0.f, 0.f};
        f16x8 afrag[4];
        #pragma unroll
        for (int ks = 0; ks < 4; ++ks) {
            int u16 = trow * 16 + (((ks << 2) + quad) ^ (trow & 15));
            afrag[ks] = *(const f16x8*)(xs + u16 * 8);
        }
        #pragma unroll
        for (int n = 0; n < 4; ++n)
            #pragma unroll
            for (int ks = 0; ks < 4; ++ks)
                acc[n] = __builtin_amdgcn_mfma_f32_16x16x32_f16(afrag[ks], bfrag[n][ks], acc[n], 0, 0, 0);

        // C layout: col(h) = l15 (+16n), row(t) = t0 + quad*4 + r
        float s0 = 0.f, s1 = 0.f, s2 = 0.f, s3 = 0.f;
        #pragma unroll
        for (int n = 0; n < 4; ++n) {
            s0 = fmaf(ftanh(acc[n][0] + w2[n]), vwr[n], s0);
            s1 = fmaf(ftanh(acc[n][1] + w2[n]), vwr[n], s1);
            s2 = fmaf(ftanh(acc[n][2] + w2[n]), vwr[n], s2);
            s3 = fmaf(ftanh(acc[n][3] + w2[n]), vwr[n], s3);
        }
        #pragma unroll
        for (int m = 1; m < 16; m <<= 1) {   // reduce over h-lanes
            s0 += __shfl_xor(s0, m);
            s1 += __shfl_xor(s1, m);
            s2 += __shfl_xor(s2, m);
            s3 += __shfl_xor(s3, m);
        }
        if (l15 == 0) {                       // apply mask at write time (L2-warm int4)
            const int tb = t0 + quad * 4;
            const int4 mv = *(const int4*)(maskb + tb);
            attL[tb]     = (mv.x == 0) ? NEGV : s0 + Vb0;
            attL[tb + 1] = (mv.y == 0) ? NEGV : s1 + Vb0;
            attL[tb + 2] = (mv.z == 0) ? NEGV : s2 + Vb0;
            attL[tb + 3] = (mv.w == 0) ? NEGV : s3 + Vb0;
        }
    }
    __syncthreads();                         // THE barrier: attL + all xs rows ready

    // ---- wave-local softmax fused with pass 2.
    // thread = (tg = lane>>2, dblk = 4wv + lane&3); its t-set: t = tg + 16k, k<13.
    // Union over tg covers 0..199 exactly once per lane&3-class.
    {
        const int tg = lane >> 2, dblk = 4 * wv + (lane & 3);
        float pv[13];
        float mx = -3e38f;
        #pragma unroll
        for (int k = 0; k < 13; ++k) {
            int t = tg + 16 * k;
            float lk = (t < Tdim) ? attL[t] : -3e38f;
            pv[k] = lk;
            mx = fmaxf(mx, lk);
        }
        #pragma unroll
        for (int off = 4; off <= 32; off <<= 1) mx = fmaxf(mx, __shfl_xor(mx, off));
        float sum = 0.f;
        #pragma unroll
        for (int k = 0; k < 13; ++k) {
            float p = __expf(pv[k] - mx);    // exp(NEGV-mx)=0, exp(-3e38)=0
            pv[k] = p;
            sum += p;
        }
        #pragma unroll
        for (int off = 4; off <= 32; off <<= 1) sum += __shfl_xor(sum, off);
        const float inv = 1.0f / sum;        // each t counted exactly once

        float o0=0.f,o1=0.f,o2=0.f,o3=0.f,o4=0.f,o5=0.f,o6=0.f,o7=0.f;
        #pragma unroll
        for (int k = 0; k < 13; ++k) {
            int t = tg + 16 * k;
            int tcl = (t < Tdim) ? t : 0;    // clamped read; weight is 0 when invalid
            float a = pv[k] * inv;
            int u16 = tcl * 16 + (dblk ^ (tcl & 15));
            f16x8 xv = *(const f16x8*)(xs + u16 * 8);
            o0 = fmaf((float)xv[0], a, o0);
            o1 = fmaf((float)xv[1], a, o1);
            o2 = fmaf((float)xv[2], a, o2);
            o3 = fmaf((float)xv[3], a, o3);
            o4 = fmaf((float)xv[4], a, o4);
            o5 = fmaf((float)xv[5], a, o5);
            o6 = fmaf((float)xv[6], a, o6);
            o7 = fmaf((float)xv[7], a, o7);
        }
        #pragma unroll
        for (int m2 = 4; m2 <= 32; m2 <<= 1) {
            o0 += __shfl_xor(o0, m2); o1 += __shfl_xor(o1, m2);
            o2 += __shfl_xor(o2, m2); o3 += __shfl_xor(o3, m2);
            o4 += __shfl_xor(o4, m2); o5 += __shfl_xor(o5, m2);
            o6 += __shfl_xor(o6, m2); o7 += __shfl_xor(o7, m2);
        }
        if (tg == 0) {                       // lanes 0..3 of each wave
            float* op = out + bs * Ddim + dblk * 8;
            *(float4*)op       = make_float4(o0, o1, o2, o3);
            *(float4*)(op + 4) = make_float4(o4, o5, o6, o7);
        }
    }
}

extern "C" void kernel_launch(void* const* d_in, const int* in_sizes, int n_in,
                              void* d_out, int out_size, void* d_ws, size_t ws_size,
                              hipStream_t stream) {
    const float* X    = (const float*)d_in[0];
    const float* z    = (const float*)d_in[1];
    const int*   mask = (const int*)d_in[2];
    const float* W1   = (const float*)d_in[3];
    const float* W2w  = (const float*)d_in[4];
    const float* W2b  = (const float*)d_in[5];
    const float* Vw   = (const float*)d_in[6];
    const float* Vb   = (const float*)d_in[7];
    float* out = (float*)d_out;

    attn_main<<<NBS, 256, 0, stream>>>(X, z, mask, W1, W2w, W2b, Vw, Vb, out);
}

// Round 4
// 472.358 us; speedup vs baseline: 1.0570x; 1.0570x over previous
//
#include <hip/hip_runtime.h>

#define Tdim 200
#define Ddim 128
#define Hdim 64
#define NBS  3200
#define NEGV (-1e10f)

typedef _Float16 f16x8 __attribute__((ext_vector_type(8)));
typedef float    floatx4 __attribute__((ext_vector_type(4)));

__device__ __forceinline__ unsigned int packf16(float a, float b) {
    _Float16 ha = (_Float16)a, hb = (_Float16)b;
    unsigned int ua = *(unsigned short*)&ha, ub = *(unsigned short*)&hb;
    return ua | (ub << 16);
}

__device__ __forceinline__ float ftanh(float x) {
    // tanh(x) = 1 - 2/(exp(2x)+1); overflow -> rcp(inf)=0 -> 1 (correct tail)
    float e = __expf(2.0f * x);
    return 1.0f - 2.0f * __builtin_amdgcn_rcpf(e + 1.0f);
}

// one block (4 waves) per (b,s). Wave-local stage->GEMM1 (no block barrier between):
// wave wv stages rows [48*wv, 48*wv+48) (wave3: 56 rows) and computes exactly the MFMA
// tiles over those rows, so its A-frag ds_reads depend only on its OWN ds_writes
// (compiler-ordered lgkmcnt). Softmax uses the scaled-sum combine (wave-local m_w, s_w
// written together) -> 4 barriers total.
//
// LDS X layout: fp16, 16B units; element (t,k) at unit t*16 + ((k>>3) ^ (t&15)),
// byte (k&7)*2. XOR swizzle: conflict-free ds_read_b128 for MFMA A-frags
// (fixed k-block, varying t) and pass-2 (fixed t, 8 consecutive d per unit).
__global__ __launch_bounds__(256, 3) void attn_main(
    const float* __restrict__ X, const float* __restrict__ z,
    const int* __restrict__ mask,
    const float* __restrict__ W1, const float* __restrict__ W2w,
    const float* __restrict__ W2b,
    const float* __restrict__ Vw, const float* __restrict__ Vb,
    float* __restrict__ out)
{
    __shared__ __align__(16) unsigned short xs[Tdim * 128];  // 51200 B, swizzled fp16
    __shared__ float attL[Tdim];
    __shared__ float red[8];
    __shared__ float w2hL[Hdim];
    // total LDS = 51200+800+32+256 = 52288 B -> 3 blocks/CU (12 waves)

    const int tid = threadIdx.x;
    const int bs  = blockIdx.x;
    const float* __restrict__ Xb = X + (size_t)bs * (Tdim * Ddim);
    const int lane = tid & 63;
    const int wv   = tid >> 6;
    const int l15  = lane & 15, quad = lane >> 4;

    // ---- early prefetch: mask value needed at softmax; held in a register so the
    // vmcnt wait lands at softmax (long complete), NOT at issue time.
    int mval = 1;
    if (tid < Tdim) mval = mask[bs * Tdim + tid];

    // ---- w2h: thread (h=tid>>2, q=tid&3) does a 32-long partial dot; combine via shfl
    {
        const int h = tid >> 2, q = tid & 3;
        const float4* zp = (const float4*)(z + (size_t)bs * 128 + q * 32);
        const float4* wp = (const float4*)(W2w + h * 128 + q * 32);
        float a = 0.f;
        #pragma unroll
        for (int i = 0; i < 8; ++i) {
            float4 zv = zp[i], wv4 = wp[i];
            a = fmaf(zv.x, wv4.x, a); a = fmaf(zv.y, wv4.y, a);
            a = fmaf(zv.z, wv4.z, a); a = fmaf(zv.w, wv4.w, a);
        }
        a += __shfl_xor(a, 1);
        a += __shfl_xor(a, 2);
        if (q == 0) w2hL[h] = a + W2b[h];
    }
    __syncthreads();                     // #1: w2hL ready (cheap, pre-staging)

    // ---- wave-local staging of this wave's rows (coalesced 1KB per wave-load)
    const int R0  = wv * 48;
    const int nIt = (wv == 3) ? 28 : 24; // rows*32/64
    #pragma unroll 4
    for (int i = 0; i < nIt; ++i) {
        int j = i * 64 + lane;
        int t = R0 + (j >> 5), dq = j & 31;
        float4 v = *(const float4*)(Xb + t * Ddim + dq * 4);
        unsigned int lo = packf16(v.x, v.y);
        unsigned int hi = packf16(v.z, v.w);
        int u16 = t * 16 + ((dq >> 1) ^ (t & 15));
        *(uint2*)((char*)xs + u16 * 16 + (dq & 1) * 8) = make_uint2(lo, hi);
    }

    // ---- B fragments from global W1 fp32 (32KB, L2-hot): B[n][k] = W1[h=n][d=k]
    f16x8 bfrag[4][4];
    #pragma unroll
    for (int n = 0; n < 4; ++n)
        #pragma unroll
        for (int ks = 0; ks < 4; ++ks) {
            const float* wp = W1 + (n * 16 + l15) * 128 + ks * 32 + quad * 8;
            float4 v0 = *(const float4*)wp;
            float4 v1 = *(const float4*)(wp + 4);
            uint4 u = make_uint4(packf16(v0.x, v0.y), packf16(v0.z, v0.w),
                                 packf16(v1.x, v1.y), packf16(v1.z, v1.w));
            bfrag[n][ks] = *(f16x8*)&u;
        }

    const float Vb0 = Vb[0];
    float vwr[4], w2[4];
    #pragma unroll
    for (int n = 0; n < 4; ++n) {
        vwr[n] = Vw[l15 + 16 * n];
        w2[n]  = w2hL[l15 + 16 * n];     // after sync #1
    }

    // ---- GEMM1 + logits on OWN rows: wave wv -> tiles [3wv, 3wv+3) (wave3: 9..12)
    // tile 12 = rows 184..199 overlaps tile 11; same wave recomputes identical
    // values serially -> benign same-bits double write, no race.
    const int mtEnd = (wv == 3) ? 13 : wv * 3 + 3;
    for (int mt = wv * 3; mt < mtEnd; ++mt) {
        const int t0 = (mt == 12) ? 184 : mt * 16;
        const int trow = t0 + l15;
        floatx4 acc[4];
        #pragma unroll
        for (int n = 0; n < 4; ++n) acc[n] = (floatx4){0.f, 0.f, 0.f, 0.f};
        f16x8 afrag[4];
        #pragma unroll
        for (int ks = 0; ks < 4; ++ks) {
            int u16 = trow * 16 + (((ks << 2) + quad) ^ (trow & 15));
            afrag[ks] = *(const f16x8*)(xs + u16 * 8);
        }
        #pragma unroll
        for (int n = 0; n < 4; ++n)
            #pragma unroll
            for (int ks = 0; ks < 4; ++ks)
                acc[n] = __builtin_amdgcn_mfma_f32_16x16x32_f16(afrag[ks], bfrag[n][ks], acc[n], 0, 0, 0);

        // C layout: col(h) = l15 (+16n), row(t) = t0 + quad*4 + r
        float s0 = 0.f, s1 = 0.f, s2 = 0.f, s3 = 0.f;
        #pragma unroll
        for (int n = 0; n < 4; ++n) {
            s0 = fmaf(ftanh(acc[n][0] + w2[n]), vwr[n], s0);
            s1 = fmaf(ftanh(acc[n][1] + w2[n]), vwr[n], s1);
            s2 = fmaf(ftanh(acc[n][2] + w2[n]), vwr[n], s2);
            s3 = fmaf(ftanh(acc[n][3] + w2[n]), vwr[n], s3);
        }
        #pragma unroll
        for (int m = 1; m < 16; m <<= 1) {   // reduce over h-lanes
            s0 += __shfl_xor(s0, m);
            s1 += __shfl_xor(s1, m);
            s2 += __shfl_xor(s2, m);
            s3 += __shfl_xor(s3, m);
        }
        if (l15 == 0) {
            const int tb = t0 + quad * 4;
            attL[tb]     = s0 + Vb0;
            attL[tb + 1] = s1 + Vb0;
            attL[tb + 2] = s2 + Vb0;
            attL[tb + 3] = s3 + Vb0;
        }
    }
    __syncthreads();                     // #2: attL + all xs rows complete

    // ---- masked softmax, scaled-sum combine: wave computes m_w AND s_w before LDS.
    float l = -3e38f;
    if (tid < Tdim) {
        l = attL[tid];
        if (mval == 0) l = NEGV;
    }
    float m = l;
    #pragma unroll
    for (int off = 32; off > 0; off >>= 1) m = fmaxf(m, __shfl_xor(m, off));
    float p = __expf(l - m);             // wave-local normalization
    float sm = p;
    #pragma unroll
    for (int off = 32; off > 0; off >>= 1) sm += __shfl_xor(sm, off);
    if (lane == 0) { red[wv] = m; red[4 + wv] = sm; }
    __syncthreads();                     // #3: all wave partials ready
    const float M = fmaxf(fmaxf(red[0], red[1]), fmaxf(red[2], red[3]));
    const float S = red[4] * __expf(red[0] - M) + red[5] * __expf(red[1] - M)
                  + red[6] * __expf(red[2] - M) + red[7] * __expf(red[3] - M);
    if (tid < Tdim) attL[tid] = p * (__expf(m - M) / S);   // == exp(l-M)/S
    __syncthreads();                     // #4

    // ---- pass 2: out[bs][d] = sum_t att[t] * X[t][d] from LDS, vectorized.
    // thread = (tgrp = lane>>2, dblk = 4*wv + lane&3): ds_read_b128 covers 8 d at one t;
    // reduction over tgrp completes within the wave via shuffles -> direct global store.
    {
        const int dblk = 4 * wv + (lane & 3);
        const int tg   = lane >> 2;
        float o0=0.f,o1=0.f,o2=0.f,o3=0.f,o4=0.f,o5=0.f,o6=0.f,o7=0.f;
        #pragma unroll 4
        for (int t = tg; t < Tdim; t += 16) {
            int u16 = t * 16 + (dblk ^ (t & 15));
            f16x8 xv = *(const f16x8*)(xs + u16 * 8);
            float a = attL[t];
            o0 = fmaf((float)xv[0], a, o0);
            o1 = fmaf((float)xv[1], a, o1);
            o2 = fmaf((float)xv[2], a, o2);
            o3 = fmaf((float)xv[3], a, o3);
            o4 = fmaf((float)xv[4], a, o4);
            o5 = fmaf((float)xv[5], a, o5);
            o6 = fmaf((float)xv[6], a, o6);
            o7 = fmaf((float)xv[7], a, o7);
        }
        #pragma unroll
        for (int m2 = 4; m2 <= 32; m2 <<= 1) {
            o0 += __shfl_xor(o0, m2); o1 += __shfl_xor(o1, m2);
            o2 += __shfl_xor(o2, m2); o3 += __shfl_xor(o3, m2);
            o4 += __shfl_xor(o4, m2); o5 += __shfl_xor(o5, m2);
            o6 += __shfl_xor(o6, m2); o7 += __shfl_xor(o7, m2);
        }
        if (tg == 0) {                   // lanes 0..3 of each wave
            float* op = out + bs * Ddim + dblk * 8;
            *(float4*)op       = make_float4(o0, o1, o2, o3);
            *(float4*)(op + 4) = make_float4(o4, o5, o6, o7);
        }
    }
}

extern "C" void kernel_launch(void* const* d_in, const int* in_sizes, int n_in,
                              void* d_out, int out_size, void* d_ws, size_t ws_size,
                              hipStream_t stream) {
    const float* X    = (const float*)d_in[0];
    const float* z    = (const float*)d_in[1];
    const int*   mask = (const int*)d_in[2];
    const float* W1   = (const float*)d_in[3];
    const float* W2w  = (const float*)d_in[4];
    const float* W2b  = (const float*)d_in[5];
    const float* Vw   = (const float*)d_in[6];
    const float* Vb   = (const float*)d_in[7];
    float* out = (float*)d_out;

    attn_main<<<NBS, 256, 0, stream>>>(X, z, mask, W1, W2w, W2b, Vw, Vb, out);
}